// Round 13
// baseline (706.467 us; speedup 1.0000x reference)
//
#include <hip/hip_runtime.h>
#include <hip/hip_bf16.h>

// VGG16 ROI head: roi_pool -> fc6(relu) -> fc7(relu) -> {cls, score}
// Weight-streaming memory-bound (fc6 W = 411 MB fp32). bf16 MFMA 16x16x32.
// R2: LDS-staged GEMM, transposed W layout [n][SK=34 k], double-buffered,
//     2-deep register prefetch, 1 barrier/half, unroll x2.
// R3: 28 k-slabs (4 blocks/CU) -> NULL (701->726): not latency-bound.
// R6: TN=128 + A staged in LDS -> 699.2 (-26.6). Partial win vs -61 predicted.
// R10 analysis: 1.64GB harness poison-fill (~250us) IS in the timed window
//     (my kernels all <248us yet total=699). fc6 ~ 220-245us = 3.3x its 68us
//     BW floor. Theory: W-read is 512B bursts @ 16KB stride -> DRAM burst
//     inefficiency (~3.3 TB/s effective vs 6.6 sequential fill).
// R10: TN=256 for fc6 (1KB bursts, thread reads 2 rows x 32B contiguous) via
//     template<TNP>; fc7/heads stay TNP=128. VGPR ~124 of 128 cap (risk:
//     spill => regression => revert). Predict fc6 -60..-80us, total ~630-660.
// R11-R15: verbatim resubmits (infra failures; R10 never measured; audits x3
//     clean). bf16-preconvert pivot is gated on this result.

typedef short short8 __attribute__((ext_vector_type(8)));   // 8 x bf16 bits
typedef float f32x4 __attribute__((ext_vector_type(4)));
typedef int   int4v __attribute__((ext_vector_type(4)));

#define SK 34      // W LDS k-stride in shorts (32 + 2 pad)
#define SKA 40     // A LDS k-stride in shorts (32 + 8 pad, keeps b128 16B-aligned)

static __device__ inline unsigned bfround(float f) {   // fp32 -> bf16 bits (round-half-up)
    return __builtin_bit_cast(unsigned, f) + 0x8000u;
}
static __device__ inline short f2bf(float f) { return (short)(bfround(f) >> 16); }

// ---------------- ROI max-pool: x (1,512,37,50) -> A (128, 25088) bf16 ----------------
__global__ void pool_kernel(const float* __restrict__ x, const float* __restrict__ rois,
                            const int* __restrict__ ridx, short* __restrict__ A) {
    const int r = blockIdx.x;
    const int y1 = (int)floorf(rois[r * 4 + 0] * 0.0625f);
    const int x1 = (int)floorf(rois[r * 4 + 1] * 0.0625f);
    const int y2 = (int)floorf(rois[r * 4 + 2] * 0.0625f);
    const int x2 = (int)floorf(rois[r * 4 + 3] * 0.0625f);
    const int h = y2 - y1 + 1, w = x2 - x1 + 1;
    const float* feat = x + (size_t)ridx[r] * (512 * 37 * 50);
    for (int t = blockIdx.y * 256 + threadIdx.x; t < 25088; t += 2048) {
        const int c = t / 49, b = t % 49, i = b / 7, j = b % 7;
        const int ys = y1 + (i * h) / 7, ye = y1 + ((i + 1) * h + 6) / 7;
        const int xs = x1 + (j * w) / 7, xe = x1 + ((j + 1) * w + 6) / 7;
        const float* f = feat + c * 1850;
        float m = -1e30f;
        for (int yy = ys; yy < ye; yy++)
            for (int xx = xs; xx < xe; xx++)
                m = fmaxf(m, f[yy * 50 + xx]);
        A[(size_t)r * 25088 + t] = f2bf(m);
    }
}

// ---------------- pack w_cls (4096x84) + w_score (4096x21) -> whd (4096x128) ----------------
__global__ void build_whd(const float* __restrict__ wc, const float* __restrict__ wsc,
                          float* __restrict__ whd) {
    const int idx = blockIdx.x * 256 + threadIdx.x;   // < 4096*128
    const int k = idx >> 7, n = idx & 127;
    float v = 0.f;
    if (n < 84) v = wc[k * 84 + n];
    else if (n < 105) v = wsc[k * 21 + (n - 84)];
    whd[idx] = v;
}

// ---------------- M=128 GEMM: part[slab] = A(128xK bf16) @ W(KxN fp32) ----------------
// block: 512 thr (8 waves = 4 m-groups x 2 n-groups). Tile 128m x TNPn, K-step 32.
// W staging: kp = tid>>5 (k-pair 0..15), nb = (tid&31)*CPT. Thread loads rows
// 2kp,2kp+1 at cols nb..nb+CPT-1 (CPT*4 B contiguous per row), converts
// fp32->bf16, packs k-pairs to dwords, writes transposed LDS [n][SK].
// A staging: am = tid>>2, kq = tid&3: one short8 -> LDS [m][SKA].
// Requires steps even and >= 4.
template<int TNP>
__global__ __launch_bounds__(512, 4)
void gemm_t(const short* __restrict__ A, const float* __restrict__ W,
            float* __restrict__ part, int K, int N, int kchunk) {
    constexpr int FN  = TNP / 32;   // n-subtiles (16 cols) per wave
    constexpr int CPT = TNP / 32;   // cols per staging thread

    __shared__ short ldsW[2][TNP * SK];    // TNP=256: 2 x 17408 B
    __shared__ short ldsA[2][128 * SKA];   // 2 x 10240 B

    const int tid = threadIdx.x;
    const int lane = tid & 63, wave = tid >> 6;
    const int l15 = lane & 15, quad = lane >> 4;
    const int wm = wave & 3;              // m-group: rows wm*32..+31
    const int wn = wave >> 2;             // n-group: cols wn*(TNP/2)..
    const int n_base = blockIdx.x * TNP;
    const int kb = blockIdx.y * kchunk;
    const int steps = kchunk >> 5;

    // W staging map
    const int kp = tid >> 5;              // 0..15
    const int nb = (tid & 31) * CPT;
    const float* gW = W + (size_t)(kb + 2 * kp) * N + n_base + nb;
    // A staging map
    const int am = tid >> 2;              // 0..127
    const int kq = tid & 3;               // k-octet
    const short* gA = A + (size_t)am * K + kb + kq * 8;

    f32x4 acc[2][FN] = {};
    f32x4 wset[2][2][CPT / 4];   // [stage][k-row of pair][float4 within row]
    short8 aglob[2];             // [stage]

    auto wload = [&](int s, int c) {
        const float* p = gW + (size_t)s * 32 * N;
#pragma unroll
        for (int r = 0; r < 2; r++)
#pragma unroll
            for (int j = 0; j < CPT / 4; j++)
                wset[c][r][j] = *(const f32x4*)(p + r * N + 4 * j);
    };
    auto aload = [&](int s, int c) {
        aglob[c] = *(const short8*)(gA + (size_t)s * 32);
    };
    auto stage = [&](int c, int buf) {   // convert wset[c] -> ldsW[buf]; aglob[c] -> ldsA[buf]
        unsigned* dst = (unsigned*)&ldsW[buf][0];
#pragma unroll
        for (int i = 0; i < CPT; i++) {
            unsigned lo = bfround(wset[c][0][i >> 2][i & 3]) >> 16;
            unsigned hi = bfround(wset[c][1][i >> 2][i & 3]) & 0xffff0000u;
            dst[(nb + i) * (SK / 2) + kp] = lo | hi;
        }
        *(short8*)(&ldsA[buf][am * SKA + kq * 8]) = aglob[c];
    };

    // prologue: stages 0,1 in flight; stage 0 into buf 0
    wload(0, 0); wload(1, 1);
    aload(0, 0); aload(1, 1);
    stage(0, 0);

    for (int s = 0; s < steps; s += 2) {
#pragma unroll
        for (int half = 0; half < 2; half++) {
            const int ss = s + half;
            const int C = half;          // compile-time 0/1
            if (ss + 2 < steps) wload(ss + 2, C);
            __syncthreads();
            // A fragments for this wave's two 16-row m-subtiles
            const short* bufA = &ldsA[C][0];
            short8 afr0 = *(const short8*)(bufA + (wm * 32 + l15) * SKA + quad * 8);
            short8 afr1 = *(const short8*)(bufA + (wm * 32 + 16 + l15) * SKA + quad * 8);
            const short* bufW = &ldsW[C][0];
#pragma unroll
            for (int fn = 0; fn < FN; fn++) {
                const int* src = (const int*)(bufW + (wn * (TNP / 2) + fn * 16 + l15) * SK + quad * 8);
                int4v t;
                t[0] = src[0]; t[1] = src[1]; t[2] = src[2]; t[3] = src[3];
                short8 bfr = __builtin_bit_cast(short8, t);
                acc[0][fn] = __builtin_amdgcn_mfma_f32_16x16x32_bf16(afr0, bfr, acc[0][fn], 0, 0, 0);
                acc[1][fn] = __builtin_amdgcn_mfma_f32_16x16x32_bf16(afr1, bfr, acc[1][fn], 0, 0, 0);
            }
            if (ss + 2 < steps) aload(ss + 2, C);
            if (ss + 1 < steps) stage(C ^ 1, C ^ 1);
        }
    }

    float* out = part + (size_t)blockIdx.y * 128 * N;
#pragma unroll
    for (int t = 0; t < 2; t++)
#pragma unroll
        for (int fn = 0; fn < FN; fn++)
#pragma unroll
            for (int r = 0; r < 4; r++) {
                const int row = wm * 32 + 16 * t + quad * 4 + r;
                const int col = n_base + wn * (TNP / 2) + fn * 16 + l15;
                out[(size_t)row * N + col] = acc[t][fn][r];
            }
}

// ---------------- slab-reduce + bias + relu -> bf16 activations ----------------
__global__ void reduce_fc(const float* __restrict__ part, const float* __restrict__ bias,
                          short* __restrict__ out, int N, int nslabs) {
    const int idx = blockIdx.x * 256 + threadIdx.x;   // < 128*N
    const int n = idx % N;
    float s = bias[n];
    for (int sl = 0; sl < nslabs; sl++) s += part[(size_t)sl * 128 * N + idx];
    s = fmaxf(s, 0.f);
    out[idx] = f2bf(s);
}

// ---------------- heads slab-reduce + bias -> d_out (cls 128x84 | score 128x21) ----------------
__global__ void reduce_heads(const float* __restrict__ part, const float* __restrict__ bc,
                             const float* __restrict__ bsc, float* __restrict__ out) {
    const int idx = blockIdx.x * 256 + threadIdx.x;
    if (idx >= 128 * 105) return;
    const int m = idx / 105, n = idx % 105;
    float s = 0.f;
    for (int sl = 0; sl < 32; sl++) s += part[sl * (128 * 128) + m * 128 + n];
    if (n < 84) out[m * 84 + n] = s + bc[n];
    else out[128 * 84 + m * 21 + (n - 84)] = s + bsc[n - 84];
}

extern "C" void kernel_launch(void* const* d_in, const int* in_sizes, int n_in,
                              void* d_out, int out_size, void* d_ws, size_t ws_size,
                              hipStream_t stream) {
    const float* x    = (const float*)d_in[0];
    const float* rois = (const float*)d_in[1];
    const int*   ridx = (const int*)d_in[2];
    const float* w6   = (const float*)d_in[3];
    const float* b6   = (const float*)d_in[4];
    const float* w7   = (const float*)d_in[5];
    const float* b7   = (const float*)d_in[6];
    const float* wc   = (const float*)d_in[7];
    const float* bc   = (const float*)d_in[8];
    const float* wsc  = (const float*)d_in[9];
    const float* bsc  = (const float*)d_in[10];
    float* out = (float*)d_out;

    char* base = (char*)d_ws;
    short* Apool = (short*)base;                         // 128*25088*2 = 6,422,528 B
    float* whd   = (float*)(base + 6422528);             // 4096*128*4  = 2,097,152 B
    short* fc6b  = (short*)(base + 8519680);             // 128*4096*2  = 1,048,576 B
    short* fc7b  = (short*)(base + 9568256);             // 128*4096*2  = 1,048,576 B
    float* slabs = (float*)(base + 10616832);            // nslabs*128*4096*4 each
    const size_t slab_base = 10616832;
    const size_t slab_bytes = (size_t)128 * 4096 * 4;    // 2 MB per slab

    // Slab counts need even steps >= 4: 25088/28=896 (28 st), /14=1792 (56),
    // /8=3136 (98). Gated on ws_size with fallback.
    int ns6 = 8, ks6 = 3136;
    if (ws_size >= slab_base + 28 * slab_bytes)      { ns6 = 28; ks6 = 896; }
    else if (ws_size >= slab_base + 14 * slab_bytes) { ns6 = 14; ks6 = 1792; }
    int ns7 = 8, ks7 = 512;
    if (ws_size >= slab_base + 16 * slab_bytes)      { ns7 = 16; ks7 = 256; }

    pool_kernel<<<dim3(128, 8), 256, 0, stream>>>(x, rois, ridx, Apool);
    build_whd<<<2048, 256, 0, stream>>>(wc, wsc, whd);

    // fc6: K=25088, N=4096, 16 n-blocks of TNP=256 (1KB W bursts)
    gemm_t<256><<<dim3(16, ns6), 512, 0, stream>>>(Apool, w6, slabs, 25088, 4096, ks6);
    reduce_fc<<<2048, 256, 0, stream>>>(slabs, b6, fc6b, 4096, ns6);

    // fc7: K=4096, N=4096, TNP=128
    gemm_t<128><<<dim3(32, ns7), 512, 0, stream>>>(fc6b, w7, slabs, 4096, 4096, ks7);
    reduce_fc<<<2048, 256, 0, stream>>>(slabs, b7, fc7b, 4096, ns7);

    // heads: K=4096, N=128 (1 n-block), 32 k-slabs (kchunk 128 -> 4 steps)
    gemm_t<128><<<dim3(1, 32), 512, 0, stream>>>(fc7b, whd, slabs, 4096, 128, 128);
    reduce_heads<<<53, 256, 0, stream>>>(slabs, bc, bsc, out);
}